// Round 15
// baseline (56.839 us; speedup 1.0000x reference)
//
#include <hip/hip_runtime.h>
#include <stdint.h>

#define N_TOT 10647
#define NB    42         // ceil(10647/256) score tiles
#define NBD   167        // decode box-groups of 64
#define NRB   (NB * NB)  // 1764 rank tile-pairs
#define NCLS  80
#define BCAP  320        // per-class bucket cap (mean ~66, huge safety margin)
#define WPB   5          // ull words per suppressor mask (BCAP/64)

typedef unsigned long long ull;

// gctr layout: [0..79]=per-class count  [80]=V
#define G_CNT  0
#define G_V    NCLS

// YOLOv3 COCO anchors, grouped by head: [0..2]=13x13, [3..5]=26x26, [6..8]=52x52
__constant__ float c_aw[9] = {116.f,156.f,373.f, 30.f,62.f,59.f, 10.f,16.f,33.f};
__constant__ float c_ah[9] = { 90.f,198.f,326.f, 61.f,45.f,119.f, 13.f,30.f,23.f};

__device__ __forceinline__ float sigmoidf_(float x) { return 1.0f / (1.0f + expf(-x)); }

// score(n) computed straight from raw inputs: conf if valid else -1.
// Constant divisors per head -> magic-mul, no real divide.
__device__ __forceinline__ float score_of(int n, const float* __restrict__ p0,
                                          const float* __restrict__ p1,
                                          const float* __restrict__ p2)
{
    float tc;
    if (n < 507) {
        int a = n / 169, rem = n - a * 169;
        tc = p0[(a * 85 + 4) * 169 + rem];
    } else if (n < 2535) {
        int m = n - 507;
        int a = m / 676, rem = m - a * 676;
        tc = p1[(a * 85 + 4) * 676 + rem];
    } else {
        int m = n - 2535;
        int a = m / 2704, rem = m - a * 2704;
        tc = p2[(a * 85 + 4) * 2704 + rem];
    }
    float cf = sigmoidf_(tc);
    return (cf >= 0.5f) ? cf : -1.0f;
}

// One dispatch, two independent roles (both read ONLY p0/p1/p2):
//   bid < NBD : decode + bucket -- 4 threads/box argmax (strict '>' keeps
//               first-max-wins), valid boxes appended to compact per-class
//               arrays (box4, conf, original idx) + V count.
//   bid >= NBD: stable-descending rank partial for tile-pair (bx,by);
//               conf computed on the fly for both sides; rank42[by][i]
//               written NON-atomically (unconditional -> no pre-zero needed).
__global__ void __launch_bounds__(256)
mega_kernel(const float* __restrict__ p0, const float* __restrict__ p1,
            const float* __restrict__ p2,
            int* __restrict__ gctr, float4* __restrict__ cbox4,
            float* __restrict__ cconf, int* __restrict__ cidx,
            int* __restrict__ rank42)
{
    __shared__ float sbest[4][64];
    __shared__ int   sbi[4][64];
    __shared__ float tile[256];
    __shared__ int   s_cnt;
    const int bid = blockIdx.x;
    const int tid = threadIdx.x;

    if (bid < NBD) {
        // ---- decode + bucket role ----
        if (tid == 0) s_cnt = 0;
        int sub  = tid >> 6;
        int lane = tid & 63;
        int n = bid * 64 + lane;
        bool inb = (n < N_TOT);
        const float* p; int H, base, lvl; float stride;
        int nn = inb ? n : 0;
        if (nn < 507)       { p = p0; H = 13; base = 0;    stride = 32.f; lvl = 0; }
        else if (nn < 2535) { p = p1; H = 26; base = 507;  stride = 16.f; lvl = 1; }
        else                { p = p2; H = 52; base = 2535; stride = 8.f;  lvl = 2; }
        int m   = nn - base;
        int HW  = H * H;
        int a   = m / HW;
        int rem = m - a * HW;
        const float* q = p + (size_t)(a * 85) * HW + rem;
        float best = -3.4e38f; int bi = 20 * sub;
        if (inb) {
            int c0 = 20 * sub;
            #pragma unroll 5
            for (int c = c0; c < c0 + 20; ++c) {
                float v = q[(size_t)(5 + c) * HW];
                if (v > best) { best = v; bi = c; }
            }
        }
        sbest[sub][lane] = best;
        sbi[sub][lane]   = bi;
        __syncthreads();
        if (sub == 0 && inb) {
            float b0 = sbest[0][lane]; int i0 = sbi[0][lane];
            #pragma unroll
            for (int s = 1; s < 4; ++s) {
                float bs = sbest[s][lane];
                if (bs > b0) { b0 = bs; i0 = sbi[s][lane]; }
            }
            float tc = q[(size_t)4*HW];
            float cf = sigmoidf_(tc);
            if (cf >= 0.5f) {
                int gy = rem / H;
                int gx = rem - gy * H;
                float tx = q[0];
                float ty = q[(size_t)HW];
                float tw = q[(size_t)2*HW];
                float th = q[(size_t)3*HW];
                float cx = (sigmoidf_(tx) + (float)gx) * stride;
                float cy = (sigmoidf_(ty) + (float)gy) * stride;
                // exp(t)*(anchor/stride)*stride == exp(t)*anchor (stride pow2)
                float bw = expf(tw) * c_aw[lvl*3 + a];
                float bh = expf(th) * c_ah[lvl*3 + a];
                int pos = atomicAdd(&gctr[G_CNT + i0], 1);
                if (pos < BCAP) {
                    cbox4[i0 * BCAP + pos] = make_float4(cx, cy, bw, bh);
                    cconf[i0 * BCAP + pos] = cf;
                    cidx[i0 * BCAP + pos]  = n;
                }
                atomicAdd(&s_cnt, 1);
            }
        }
        __syncthreads();
        if (tid == 0 && s_cnt) atomicAdd(&gctr[G_V], s_cnt);
    } else {
        // ---- rank partial role ----
        int rb = bid - NBD;
        int bx = rb / NB;
        int by = rb - bx * NB;
        int j0 = by * 256;
        int jj = j0 + tid;
        tile[tid] = (jj < N_TOT) ? score_of(jj, p0, p1, p2) : -2.0f;
        __syncthreads();
        int i = bx * 256 + tid;
        if (i >= N_TOT) return;
        float si = score_of(i, p0, p1, p2);
        if (si < 0.0f) return;          // invalid i: partial never read
        int r = 0;
        #pragma unroll 8
        for (int t = 0; t < 256; ++t) {
            float sj = tile[t];
            r += (sj > si || (sj == si && (j0 + t) < i)) ? 1 : 0;
        }
        rank42[(size_t)by * N_TOT + i] = r;   // unconditional (no pre-zero)
    }
}

// One block per class, fully independent (NMS edges are same-class only):
// load own compact list; member rank = sum of 42 partials (gathered);
// n x n suppressor bitmasks in LDS (b suppresses a iff rank_b < rank_a &&
// IoU > 0.5) -> LDS Jacobi fixpoint (unique fixpoint == greedy by induction
// over the rank-ordered DAG; depth-d nodes final after d+1 rounds; cap n+2 =>
// exact) -> write own output rows (row = global rank) + a chunk of the
// invalid-row region [V, N_TOT).
__global__ void __launch_bounds__(256)
class_nms_kernel(const float4* __restrict__ cbox4, const float* __restrict__ cconf,
                 const int* __restrict__ cidx, const int* __restrict__ rank42,
                 const int* __restrict__ gctr, float* __restrict__ out)
{
    __shared__ float bcx[BCAP], bcy[BCAP], bw_[BCAP], bh_[BCAP], bcf[BCAP];
    __shared__ uint16_t brank[BCAP];
    __shared__ ull smask[BCAP][WPB];
    __shared__ ull keepm[WPB], nxtm[WPB];
    __shared__ int s_changed;
    const int c   = blockIdx.x;
    const int tid = threadIdx.x;
    const int n   = min(gctr[G_CNT + c], BCAP);
    const int V   = gctr[G_V];
    for (int a = tid; a < n; a += 256) {
        float4 b4 = cbox4[c * BCAP + a];
        bcx[a] = b4.x; bcy[a] = b4.y; bw_[a] = b4.z; bh_[a] = b4.w;
        bcf[a] = cconf[c * BCAP + a];
        int idx = cidx[c * BCAP + a];
        int r = 0;
        #pragma unroll
        for (int s = 0; s < NB; ++s) r += rank42[(size_t)s * N_TOT + idx];
        brank[a] = (uint16_t)r;
    }
    __syncthreads();
    // ---- suppressor masks: smask[a] bit b iff rank_b<rank_a && IoU>0.5 ----
    for (int a = tid; a < n; a += 256) {
        float ax1 = bcx[a] - bw_[a]*0.5f, ay1 = bcy[a] - bh_[a]*0.5f;
        float ax2 = bcx[a] + bw_[a]*0.5f, ay2 = bcy[a] + bh_[a]*0.5f;
        float aar = bw_[a] * bh_[a];
        int ra = brank[a];
        ull msk[WPB] = {0,0,0,0,0};
        for (int b = 0; b < n; ++b) {
            if (b == a) continue;
            if (brank[b] >= ra) continue;
            float bx1 = bcx[b] - bw_[b]*0.5f, by1 = bcy[b] - bh_[b]*0.5f;
            float bx2 = bcx[b] + bw_[b]*0.5f, by2 = bcy[b] + bh_[b]*0.5f;
            float xx1 = fmaxf(ax1, bx1);
            float yy1 = fmaxf(ay1, by1);
            float xx2 = fminf(ax2, bx2);
            float yy2 = fminf(ay2, by2);
            float w = fmaxf(xx2 - xx1, 0.0f);
            float h = fmaxf(yy2 - yy1, 0.0f);
            float inter = w * h;
            float uni   = aar + bw_[b]*bh_[b] - inter;
            float iou   = inter / fmaxf(uni, 1e-9f);
            if (iou > 0.5f) msk[b >> 6] |= (1ull << (b & 63));
        }
        #pragma unroll
        for (int w = 0; w < WPB; ++w) smask[a][w] = msk[w];
    }
    if (tid < WPB) {
        int rem = n - (tid << 6);
        keepm[tid] = (rem >= 64) ? ~0ull : ((rem > 0) ? ((1ull << rem) - 1ull) : 0ull);
    }
    __syncthreads();
    // ---- LDS Jacobi fixpoint ----
    for (int round = 0; round <= n + 2 && n > 0; ++round) {
        if (tid < WPB) nxtm[tid] = 0ull;
        if (tid == 0) s_changed = 0;
        __syncthreads();
        for (int a = tid; a < n; a += 256) {
            ull sup = 0ull;
            #pragma unroll
            for (int w = 0; w < WPB; ++w) sup |= (smask[a][w] & keepm[w]);
            if (sup == 0ull) atomicOr(&nxtm[a >> 6], 1ull << (a & 63));
        }
        __syncthreads();
        if (tid < WPB) {
            if (nxtm[tid] != keepm[tid]) { s_changed = 1; keepm[tid] = nxtm[tid]; }
        }
        __syncthreads();
        if (!s_changed) break;
        __syncthreads();
    }
    // ---- write own rows ----
    for (int a = tid; a < n; a += 256) {
        int r = brank[a];
        bool kept = (keepm[a >> 6] >> (a & 63)) & 1ull;
        float v0=0.f,v1=0.f,v2=0.f,v3=0.f,v4=0.f,v5=0.f;
        if (kept) {
            v0 = bcx[a]; v1 = bcy[a]; v2 = bw_[a]; v3 = bh_[a];
            v4 = bcf[a]; v5 = (float)c;
        }
        out[r*6+0]=v0; out[r*6+1]=v1; out[r*6+2]=v2;
        out[r*6+3]=v3; out[r*6+4]=v4; out[r*6+5]=v5;
    }
    // ---- zero a chunk of the invalid region [V, N_TOT) ----
    int tail  = N_TOT - V;
    int chunk = (tail + NCLS - 1) / NCLS;
    int rbeg  = V + c * chunk;
    int rend  = min(rbeg + chunk, N_TOT);
    for (int r = rbeg + tid; r < rend; r += 256) {
        out[r*6+0]=0.f; out[r*6+1]=0.f; out[r*6+2]=0.f;
        out[r*6+3]=0.f; out[r*6+4]=0.f; out[r*6+5]=0.f;
    }
}

extern "C" void kernel_launch(void* const* d_in, const int* in_sizes, int n_in,
                              void* d_out, int out_size, void* d_ws, size_t ws_size,
                              hipStream_t stream) {
    const float* p0 = (const float*)d_in[0];
    const float* p1 = (const float*)d_in[1];
    const float* p2 = (const float*)d_in[2];
    float* out = (float*)d_out;
    char* ws = (char*)d_ws;
    const int N = N_TOT;

    int* gctr = (int*)ws;                              // 81 ints
    float4* cbox4 = (float4*)(((uintptr_t)(gctr + NCLS + 1) + 15) & ~(uintptr_t)15);
    float*  cconf = (float*)(cbox4 + NCLS * BCAP);     // 80*320 floats
    int*    cidx  = (int*)(cconf + NCLS * BCAP);       // 80*320 ints
    int*    rank42 = cidx + NCLS * BCAP;               // 42N ints = 1.79 MB

    hipMemsetAsync(gctr, 0, (NCLS + 1) * sizeof(int), stream);
    mega_kernel<<<NBD + NRB, 256, 0, stream>>>(p0, p1, p2, gctr, cbox4, cconf,
                                               cidx, rank42);
    class_nms_kernel<<<NCLS, 256, 0, stream>>>(cbox4, cconf, cidx, rank42, gctr, out);
}

// Round 16
// 46.854 us; speedup vs baseline: 1.2131x; 1.2131x over previous
//
#include <hip/hip_runtime.h>
#include <stdint.h>

#define N_TOT 10647
#define NB    42         // ceil(10647/256) score tiles
#define NBD   167        // decode box-groups of 64
#define NCLS  80
#define BCAP  320        // per-class bucket cap (mean ~66, huge safety margin)
#define WPB   5          // ull words per suppressor mask (BCAP/64)

typedef unsigned long long ull;

// gctr layout: [0..79]=per-class count  [80]=V
#define G_CNT  0
#define G_V    NCLS

// YOLOv3 COCO anchors, grouped by head: [0..2]=13x13, [3..5]=26x26, [6..8]=52x52
__constant__ float c_aw[9] = {116.f,156.f,373.f, 30.f,62.f,59.f, 10.f,16.f,33.f};
__constant__ float c_ah[9] = { 90.f,198.f,326.f, 61.f,45.f,119.f, 13.f,30.f,23.f};

__device__ __forceinline__ float sigmoidf_(float x) { return 1.0f / (1.0f + expf(-x)); }

// 4 threads per box: sub s (=tid>>6) scans classes [20s,20s+20); lane (=tid&63)
// picks the box. Strict '>' everywhere preserves jnp.argmax first-max-wins.
// Sub-0 lanes zero rank[]; block 0 zeroes gctr (consumed next kernel).
__global__ void __launch_bounds__(256)
decode_kernel(const float* __restrict__ p0, const float* __restrict__ p1,
              const float* __restrict__ p2,
              float* __restrict__ box, float* __restrict__ conf,
              float* __restrict__ score, int* __restrict__ cls,
              int* __restrict__ rank, int* __restrict__ gctr)
{
    __shared__ float sbest[4][64];
    __shared__ int   sbi[4][64];
    if (blockIdx.x == 0 && threadIdx.x <= NCLS) gctr[threadIdx.x] = 0;
    int sub  = threadIdx.x >> 6;
    int lane = threadIdx.x & 63;
    int n = blockIdx.x * 64 + lane;
    bool inb = (n < N_TOT);
    const float* p; int H, base, lvl; float stride;
    int nn = inb ? n : 0;
    if (nn < 507)       { p = p0; H = 13; base = 0;    stride = 32.f; lvl = 0; }
    else if (nn < 2535) { p = p1; H = 26; base = 507;  stride = 16.f; lvl = 1; }
    else                { p = p2; H = 52; base = 2535; stride = 8.f;  lvl = 2; }
    int m   = nn - base;
    int HW  = H * H;
    int a   = m / HW;
    int rem = m - a * HW;
    const float* q = p + (size_t)(a * 85) * HW + rem;
    float best = -3.4e38f; int bi = 20 * sub;
    if (inb) {
        int c0 = 20 * sub;
        #pragma unroll 5
        for (int c = c0; c < c0 + 20; ++c) {
            float v = q[(size_t)(5 + c) * HW];
            if (v > best) { best = v; bi = c; }
        }
    }
    sbest[sub][lane] = best;
    sbi[sub][lane]   = bi;
    __syncthreads();
    if (sub == 0 && inb) {
        rank[n] = 0;
        float b0 = sbest[0][lane]; int i0 = sbi[0][lane];
        #pragma unroll
        for (int s = 1; s < 4; ++s) {
            float bs = sbest[s][lane];
            if (bs > b0) { b0 = bs; i0 = sbi[s][lane]; }
        }
        int gy = rem / H;
        int gx = rem - gy * H;
        float tx = q[0];
        float ty = q[(size_t)HW];
        float tw = q[(size_t)2*HW];
        float th = q[(size_t)3*HW];
        float tc = q[(size_t)4*HW];
        float cx = (sigmoidf_(tx) + (float)gx) * stride;
        float cy = (sigmoidf_(ty) + (float)gy) * stride;
        // exp(t)*(anchor/stride)*stride == exp(t)*anchor exactly (stride pow2)
        float bw = expf(tw) * c_aw[lvl*3 + a];
        float bh = expf(th) * c_ah[lvl*3 + a];
        float cf = sigmoidf_(tc);
        box[n*4+0] = cx; box[n*4+1] = cy; box[n*4+2] = bw; box[n*4+3] = bh;
        conf[n] = cf;
        cls[n]  = i0;
        score[n] = (cf >= 0.5f) ? cf : -1.0f;
    }
}

// Fused rank + bucket dispatch. The two roles are INDEPENDENT (both consume
// only decode outputs), so they share one kernel with no intra-kernel sync:
//   by <  NB : stable-descending rank tile (bx,by) -> atomicAdd rank[i]
//   by == NB : compaction tile bx -> append (box4, conf, ORIGINAL idx) to
//              per-class arrays + V count. class_nms gathers rank[idx] later.
__global__ void __launch_bounds__(256)
rank_bucket_kernel(const float* __restrict__ score, const float* __restrict__ box,
                   const float* __restrict__ conf, const int* __restrict__ cls,
                   int* __restrict__ rank, int* __restrict__ gctr,
                   float4* __restrict__ cbox4, float* __restrict__ cconf,
                   int* __restrict__ cidx)
{
    __shared__ float tile[256];
    __shared__ int s_cnt;
    const int tid = threadIdx.x;
    if (blockIdx.y < NB) {
        // ---- rank role ----
        int i   = blockIdx.x * 256 + tid;
        int j0  = blockIdx.y * 256;
        int jj  = j0 + tid;
        tile[tid] = (jj < N_TOT) ? score[jj] : -2.0f;   // sentinel < all scores
        __syncthreads();
        float si = (i < N_TOT) ? score[i] : -2.0f;
        if (i >= N_TOT || si < 0.0f) return;            // invalid i: rank unused
        int r = 0;
        #pragma unroll 8
        for (int t = 0; t < 256; ++t) {
            float sj = tile[t];
            r += (sj > si || (sj == si && (j0 + t) < i)) ? 1 : 0;
        }
        if (r) atomicAdd(&rank[i], r);
    } else {
        // ---- bucket role (coalesced; ~66 appends per class counter) ----
        if (tid == 0) s_cnt = 0;
        __syncthreads();
        int i = blockIdx.x * 256 + tid;
        if (i < N_TOT && score[i] >= 0.0f) {
            int c = cls[i];
            int pos = atomicAdd(&gctr[G_CNT + c], 1);
            if (pos < BCAP) {
                cbox4[c * BCAP + pos] = *(const float4*)&box[i * 4];
                cconf[c * BCAP + pos] = conf[i];
                cidx[c * BCAP + pos]  = i;
            }
            atomicAdd(&s_cnt, 1);
        }
        __syncthreads();
        if (tid == 0 && s_cnt) atomicAdd(&gctr[G_V], s_cnt);
    }
}

// One block per class, fully independent (NMS edges are same-class only):
// load own compact list (contiguous; global rank gathered via rank[cidx]) ->
// n x n suppressor bitmasks in LDS (b suppresses a iff rank_b < rank_a &&
// IoU > 0.5) -> LDS Jacobi fixpoint (unique fixpoint == greedy by induction
// over the rank-ordered DAG; depth-d nodes final after d+1 rounds; cap n+2 =>
// exact) -> write own output rows (row = global rank) + a chunk of the
// invalid-row region [V, N_TOT).
__global__ void __launch_bounds__(256)
class_nms_kernel(const float4* __restrict__ cbox4, const float* __restrict__ cconf,
                 const int* __restrict__ cidx, const int* __restrict__ rank,
                 const int* __restrict__ gctr, float* __restrict__ out)
{
    __shared__ float bcx[BCAP], bcy[BCAP], bw_[BCAP], bh_[BCAP], bcf[BCAP];
    __shared__ uint16_t brank[BCAP];
    __shared__ ull smask[BCAP][WPB];
    __shared__ ull keepm[WPB], nxtm[WPB];
    __shared__ int s_changed;
    const int c   = blockIdx.x;
    const int tid = threadIdx.x;
    const int n   = min(gctr[G_CNT + c], BCAP);
    const int V   = gctr[G_V];
    for (int a = tid; a < n; a += 256) {
        float4 b4 = cbox4[c * BCAP + a];
        bcx[a] = b4.x; bcy[a] = b4.y; bw_[a] = b4.z; bh_[a] = b4.w;
        bcf[a] = cconf[c * BCAP + a];
        brank[a] = (uint16_t)rank[cidx[c * BCAP + a]];
    }
    __syncthreads();
    // ---- suppressor masks: smask[a] bit b iff rank_b<rank_a && IoU>0.5 ----
    for (int a = tid; a < n; a += 256) {
        float ax1 = bcx[a] - bw_[a]*0.5f, ay1 = bcy[a] - bh_[a]*0.5f;
        float ax2 = bcx[a] + bw_[a]*0.5f, ay2 = bcy[a] + bh_[a]*0.5f;
        float aar = bw_[a] * bh_[a];
        int ra = brank[a];
        ull msk[WPB] = {0,0,0,0,0};
        for (int b = 0; b < n; ++b) {
            if (b == a) continue;
            if (brank[b] >= ra) continue;
            float bx1 = bcx[b] - bw_[b]*0.5f, by1 = bcy[b] - bh_[b]*0.5f;
            float bx2 = bcx[b] + bw_[b]*0.5f, by2 = bcy[b] + bh_[b]*0.5f;
            float xx1 = fmaxf(ax1, bx1);
            float yy1 = fmaxf(ay1, by1);
            float xx2 = fminf(ax2, bx2);
            float yy2 = fminf(ay2, by2);
            float w = fmaxf(xx2 - xx1, 0.0f);
            float h = fmaxf(yy2 - yy1, 0.0f);
            float inter = w * h;
            float uni   = aar + bw_[b]*bh_[b] - inter;
            float iou   = inter / fmaxf(uni, 1e-9f);
            if (iou > 0.5f) msk[b >> 6] |= (1ull << (b & 63));
        }
        #pragma unroll
        for (int w = 0; w < WPB; ++w) smask[a][w] = msk[w];
    }
    if (tid < WPB) {
        int rem = n - (tid << 6);
        keepm[tid] = (rem >= 64) ? ~0ull : ((rem > 0) ? ((1ull << rem) - 1ull) : 0ull);
    }
    __syncthreads();
    // ---- LDS Jacobi fixpoint ----
    for (int round = 0; round <= n + 2 && n > 0; ++round) {
        if (tid < WPB) nxtm[tid] = 0ull;
        if (tid == 0) s_changed = 0;
        __syncthreads();
        for (int a = tid; a < n; a += 256) {
            ull sup = 0ull;
            #pragma unroll
            for (int w = 0; w < WPB; ++w) sup |= (smask[a][w] & keepm[w]);
            if (sup == 0ull) atomicOr(&nxtm[a >> 6], 1ull << (a & 63));
        }
        __syncthreads();
        if (tid < WPB) {
            if (nxtm[tid] != keepm[tid]) { s_changed = 1; keepm[tid] = nxtm[tid]; }
        }
        __syncthreads();
        if (!s_changed) break;
        __syncthreads();
    }
    // ---- write own rows ----
    for (int a = tid; a < n; a += 256) {
        int r = brank[a];
        bool kept = (keepm[a >> 6] >> (a & 63)) & 1ull;
        float v0=0.f,v1=0.f,v2=0.f,v3=0.f,v4=0.f,v5=0.f;
        if (kept) {
            v0 = bcx[a]; v1 = bcy[a]; v2 = bw_[a]; v3 = bh_[a];
            v4 = bcf[a]; v5 = (float)c;
        }
        out[r*6+0]=v0; out[r*6+1]=v1; out[r*6+2]=v2;
        out[r*6+3]=v3; out[r*6+4]=v4; out[r*6+5]=v5;
    }
    // ---- zero a chunk of the invalid region [V, N_TOT) ----
    int tail  = N_TOT - V;
    int chunk = (tail + NCLS - 1) / NCLS;
    int rbeg  = V + c * chunk;
    int rend  = min(rbeg + chunk, N_TOT);
    for (int r = rbeg + tid; r < rend; r += 256) {
        out[r*6+0]=0.f; out[r*6+1]=0.f; out[r*6+2]=0.f;
        out[r*6+3]=0.f; out[r*6+4]=0.f; out[r*6+5]=0.f;
    }
}

extern "C" void kernel_launch(void* const* d_in, const int* in_sizes, int n_in,
                              void* d_out, int out_size, void* d_ws, size_t ws_size,
                              hipStream_t stream) {
    const float* p0 = (const float*)d_in[0];
    const float* p1 = (const float*)d_in[1];
    const float* p2 = (const float*)d_in[2];
    float* out = (float*)d_out;
    char* ws = (char*)d_ws;
    const int N = N_TOT;

    float* box   = (float*)ws;           // 4N (16B aligned)
    float* conf  = box + 4*N;            // N
    float* score = conf + N;             // N
    int* cls   = (int*)(score + N);      // N
    int* rank  = cls + N;                // N
    int* gctr  = rank + N;               // 81 ints
    float4* cbox4 = (float4*)(((uintptr_t)(gctr + NCLS + 1) + 15) & ~(uintptr_t)15);
    float*  cconf = (float*)(cbox4 + NCLS * BCAP);   // 80*320 floats
    int*    cidx  = (int*)(cconf + NCLS * BCAP);     // 80*320 ints

    decode_kernel<<<NBD, 256, 0, stream>>>(p0, p1, p2, box, conf, score, cls, rank, gctr);
    rank_bucket_kernel<<<dim3(NB, NB + 1), 256, 0, stream>>>(score, box, conf, cls,
                                                             rank, gctr, cbox4, cconf, cidx);
    class_nms_kernel<<<NCLS, 256, 0, stream>>>(cbox4, cconf, cidx, rank, gctr, out);
}